// Round 4
// baseline (558.953 us; speedup 1.0000x reference)
//
#include <hip/hip_runtime.h>
#include <hip/hip_bf16.h>
#include <cstdint>

// Problem: B=32, S=2048, H=1024
//   c[b,o]   = hidden[b,:].Wh[o,:] + bias[o]        (Wh = W_attn[:, :H])
//   e[b,s,o] = enc[b,s,:].We[o,:]                   (We = W_attn[:, H:])
//   logit[b,s] = sum_o tanh(e + c) * v[o];  out = softmax over s
//
// R6 (on R5's BM=128 x BN=512 tile, wave = 128 rows x 64 cols):
//  - B-frag prefetch depth 2 (2 static register sets, reload t+2) so L2
//    latency gets ~2 steps of MFMA cover instead of <1.
//  - A-staging in 4 batches/phase (4 rows each): pack+ds_write_b128 of batch s
//    interleaved after step s's MFMA cluster, loads issued 2 steps ahead.
//    No serial phase tail; b128 writes are bank-structural (8/bank).
//  - XCD-paired block swizzle: (strip, nhalf 0/1) share an XCD -> enc strip's
//    second read L2-hits.

#define HDIM 1024
#define SDIM 2048
#define MTOT 65536

typedef __attribute__((ext_vector_type(8))) short short8;   // 8 bf16
typedef __attribute__((ext_vector_type(4))) float floatx4;  // MFMA acc

__device__ __forceinline__ unsigned short f2bf(float f) {
    unsigned int u = __float_as_uint(f);
    u += 0x7fffu + ((u >> 16) & 1u);   // RNE
    return (unsigned short)(u >> 16);
}
__device__ __forceinline__ unsigned int pack2(float a, float b) {
    return (unsigned int)f2bf(a) | ((unsigned int)f2bf(b) << 16);
}
__device__ __forceinline__ float fast_tanh(float x) {
    float e2 = __expf(2.f * x);
    return 1.f - 2.f * __builtin_amdgcn_rcpf(e2 + 1.f);
}

// ---- merged prep kernel ----
// blocks [0,512):   convert We (W_attn[:, H:2H]) into fragment-major bf16 Wbf2
// blocks [512,1536): c[b,o] = hidden[b,:].Wh[o,:] + bias[o], one block per o
__global__ __launch_bounds__(256) void prep(const float* __restrict__ W,
                                            unsigned short* __restrict__ Wbf2,
                                            const float* __restrict__ hid,
                                            const float* __restrict__ bias,
                                            float* __restrict__ c) {
    __shared__ float red[4][32];
    if (blockIdx.x < 512) {
        int T = blockIdx.x * 256 + threadIdx.x;   // [0, 131072): (n, k8)
        int n  = T >> 7;
        int k8 = T & 127;
        int k  = k8 * 8;
        const float4* src = (const float4*)(W + (size_t)n * 2048 + 1024 + k);
        float4 f0 = src[0], f1 = src[1];
        int jt = n >> 4, lc = n & 15, kc = k8 >> 2, g = k8 & 3;
        uint4 u;
        u.x = pack2(f0.x, f0.y); u.y = pack2(f0.z, f0.w);
        u.z = pack2(f1.x, f1.y); u.w = pack2(f1.z, f1.w);
        *(uint4*)(Wbf2 + (size_t)(jt * 32 + kc) * 512 + (g * 16 + lc) * 8) = u;
    } else {
        const int o = blockIdx.x - 512;
        const int wave = threadIdx.x >> 6, lane = threadIdx.x & 63;
        const int k = wave * 256 + lane * 4;
        const float4 wv = *(const float4*)(W + (size_t)o * 2048 + k);
        float acc[32];
#pragma unroll
        for (int b = 0; b < 32; ++b) {
            const float4 h = *(const float4*)(hid + b * HDIM + k);
            acc[b] = wv.x * h.x + wv.y * h.y + wv.z * h.z + wv.w * h.w;
        }
#pragma unroll
        for (int b = 0; b < 32; ++b) {
            float x = acc[b];
            for (int off = 32; off; off >>= 1) x += __shfl_xor(x, off);
            if (lane == 0) red[wave][b] = x;
        }
        __syncthreads();
        if (threadIdx.x < 32) {
            int b = threadIdx.x;
            c[b * HDIM + o] = red[0][b] + red[1][b] + red[2][b] + red[3][b] + bias[o];
        }
    }
}

// ---- fused GEMM + tanh + v-dot ----
#define PHN 8     // K phases
#define PHK 128   // K per phase

__global__ __launch_bounds__(512, 2) void attn_fused(const float* __restrict__ enc,
                                                     const unsigned short* __restrict__ Wbf2,
                                                     const float* __restrict__ c,
                                                     const float* __restrict__ v,
                                                     float* __restrict__ part) {
    // slab: 128 rows x 128 k bf16, row stride 128 ushorts (256B); 16B chunk c16
    // of row r stored at slot (c16 ^ (r&7)).
    __shared__ __align__(16) unsigned short slab[2][128 * 128];   // 2 x 32 KB

    const int tid  = threadIdx.x;
    const int lane = tid & 63;
    const int wave = tid >> 6;    // 0..7
    const int grp  = lane >> 4;   // 0..3
    const int lc   = lane & 15;

    // XCD-paired decode: phys j -> XCD j%8; (strip, nhalf=0/1) land on the
    // same XCD 8 dispatch-slots apart. Bijective for 1024 blocks.
    const int j     = blockIdx.x;
    const int strip = (j & 7) * 64 + (j >> 4);   // 0..511
    const int nhalf = (j >> 3) & 1;
    const int m0 = strip * 128;
    const int b  = m0 >> 11;      // batch (128-row strips never straddle b)
    const int cb = nhalf * 512 + wave * 64;      // wave's global col base

    // staging geometry: wave rows [wave*16, +16); batch q in [0,4) = 4 rows.
    //   lane: row = q*4 + (lane>>4), covers floats [ (lane&15)*8, +8 )
    const int s_row4 = lane >> 4;        // row within batch
    const int s_c16  = lane & 15;        // 16B-bf16 chunk index within row
    const float* encw = enc + (size_t)(m0 + wave * 16 + s_row4) * HDIM + s_c16 * 8;

    floatx4 acc[8][4];
#pragma unroll
    for (int i = 0; i < 8; ++i)
#pragma unroll
        for (int jj = 0; jj < 4; ++jj) acc[i][jj] = (floatx4){0.f, 0.f, 0.f, 0.f};

    const short8* Bfr = (const short8*)Wbf2;
    const int jt0 = nhalf * 32 + wave * 4;    // wave's first 16-col B tile

    // ld sets: 2 batches in flight, 2 float4 each (32B contiguous per lane)
    float4 ldq[2][2];
    // write helper values
    const int w_rowb = wave * 16 + s_row4;    // + q*4 at use site

#define ISSUE_BATCH(par, q, pn)                                               \
    {                                                                         \
        const float* src = encw + (size_t)(q) * 4 * HDIM + (pn) * PHK;        \
        ldq[par][0] = *(const float4*)(src);                                  \
        ldq[par][1] = *(const float4*)(src + 4);                              \
    }
#define WRITE_BATCH(par, q, buf)                                              \
    {                                                                         \
        int row  = w_rowb + (q) * 4;                                          \
        int slot = s_c16 ^ (row & 7);                                         \
        uint4 u;                                                              \
        u.x = pack2(ldq[par][0].x, ldq[par][0].y);                            \
        u.y = pack2(ldq[par][0].z, ldq[par][0].w);                            \
        u.z = pack2(ldq[par][1].x, ldq[par][1].y);                            \
        u.w = pack2(ldq[par][1].z, ldq[par][1].w);                            \
        *(uint4*)(&slab[buf][row * 128 + slot * 8]) = u;                      \
    }

    // prologue: stage phase 0 into buf 0
    ISSUE_BATCH(0, 0, 0)
    ISSUE_BATCH(1, 1, 0)
    WRITE_BATCH(0, 0, 0)
    ISSUE_BATCH(0, 2, 0)
    WRITE_BATCH(1, 1, 0)
    ISSUE_BATCH(1, 3, 0)
    WRITE_BATCH(0, 2, 0)
    WRITE_BATCH(1, 3, 0)

    // B prefetch depth 2: Bv[t&1] holds frags for K-32 step t
    short8 Bv[2][4];
#pragma unroll
    for (int jj = 0; jj < 4; ++jj) {
        Bv[0][jj] = Bfr[(size_t)((jt0 + jj) * 32 + 0) * 64 + lane];
        Bv[1][jj] = Bfr[(size_t)((jt0 + jj) * 32 + 1) * 64 + lane];
    }

#pragma unroll 1
    for (int p = 0; p < PHN; ++p) {
        __syncthreads();   // slab[p&1] fully written

        if (p < PHN - 1) {
            ISSUE_BATCH(0, 0, p + 1)
            ISSUE_BATCH(1, 1, p + 1)
        }

        const unsigned short* sl = slab[p & 1];
#pragma unroll
        for (int s = 0; s < 4; ++s) {                 // K-32 step t = p*4+s
            const int t  = p * 4 + s;
            const int kc = s;
            short8 af[8];
#pragma unroll
            for (int i = 0; i < 8; ++i) {
                int row  = i * 16 + lc;
                int slot = (kc * 4 + grp) ^ (lc & 7);
                af[i] = *(const short8*)(sl + row * 128 + slot * 8);
            }
#pragma unroll
            for (int i = 0; i < 8; ++i)
#pragma unroll
                for (int jj = 0; jj < 4; ++jj)
                    acc[i][jj] = __builtin_amdgcn_mfma_f32_16x16x32_bf16(
                        af[i], Bv[s & 1][jj], acc[i][jj], 0, 0, 0);
            // reload this B set for step t+2 (its frags were just consumed)
            {
                const int kcg = (t + 2 < 32) ? (t + 2) : 31;
#pragma unroll
                for (int jj = 0; jj < 4; ++jj)
                    Bv[s & 1][jj] = Bfr[(size_t)((jt0 + jj) * 32 + kcg) * 64 + lane];
            }
            // staging for phase p+1: write batch s (loads >=2 steps old),
            // then issue batch s+2 into the freed set
            if (p < PHN - 1) {
                if (s == 0)      { WRITE_BATCH(0, 0, (p + 1) & 1) ISSUE_BATCH(0, 2, p + 1) }
                else if (s == 1) { WRITE_BATCH(1, 1, (p + 1) & 1) ISSUE_BATCH(1, 3, p + 1) }
                else if (s == 2) { WRITE_BATCH(0, 2, (p + 1) & 1) }
                else             { WRITE_BATCH(1, 3, (p + 1) & 1) }
            }
        }
    }

    // epilogue: rowsum over this wave's 64 cols, tanh(e + c) * v
    float rowsum[8][4];
#pragma unroll
    for (int i = 0; i < 8; ++i)
#pragma unroll
        for (int r = 0; r < 4; ++r) rowsum[i][r] = 0.f;

#pragma unroll
    for (int jj = 0; jj < 4; ++jj) {
        const int n  = cb + jj * 16 + lc;
        const float vn = v[n];
        const float cv = c[b * HDIM + n];
#pragma unroll
        for (int i = 0; i < 8; ++i)
#pragma unroll
            for (int r = 0; r < 4; ++r)
                rowsum[i][r] = fmaf(fast_tanh(acc[i][jj][r] + cv), vn,
                                    rowsum[i][r]);
    }

    // in-block reduction across the 8 waves (disjoint 64-col slices, same
    // 128 rows). red overlays slab (no LDS reads after final barrier).
    __syncthreads();
    float* red = (float*)slab;
#pragma unroll
    for (int i = 0; i < 8; ++i)
#pragma unroll
        for (int r = 0; r < 4; ++r) {
            float x = rowsum[i][r];
            x += __shfl_xor(x, 8);
            x += __shfl_xor(x, 4);
            x += __shfl_xor(x, 2);
            x += __shfl_xor(x, 1);
            if (lc == 0) red[wave * 128 + i * 16 + grp * 4 + r] = x;
        }
    __syncthreads();
    if (tid < 128) {
        float ssum = 0.f;
#pragma unroll
        for (int w = 0; w < 8; ++w) ssum += red[w * 128 + tid];
        part[(size_t)nhalf * MTOT + m0 + tid] = ssum;
    }
#undef ISSUE_BATCH
#undef WRITE_BATCH
}

// ---- softmax over S=2048 per batch, summing 2 partial col-half slices ----
__global__ __launch_bounds__(256) void softmax_k(const float* __restrict__ part,
                                                 float* __restrict__ out) {
    __shared__ float wred[4];
    const int bb = blockIdx.x;
    const int tid = threadIdx.x;
    const int wave = tid >> 6, lane = tid & 63;

    float vals[8];
    float lmax = -INFINITY;
#pragma unroll
    for (int q = 0; q < 8; ++q) {
        const size_t idx = (size_t)bb * SDIM + q * 256 + tid;
        vals[q] = part[idx] + part[(size_t)MTOT + idx];
        lmax = fmaxf(lmax, vals[q]);
    }
    for (int off = 32; off; off >>= 1) lmax = fmaxf(lmax, __shfl_xor(lmax, off));
    if (lane == 0) wred[wave] = lmax;
    __syncthreads();
    lmax = fmaxf(fmaxf(wred[0], wred[1]), fmaxf(wred[2], wred[3]));
    __syncthreads();

    float e[8];
    float s = 0.f;
#pragma unroll
    for (int q = 0; q < 8; ++q) {
        e[q] = __expf(vals[q] - lmax);
        s += e[q];
    }
    for (int off = 32; off; off >>= 1) s += __shfl_xor(s, off);
    if (lane == 0) wred[wave] = s;
    __syncthreads();
    s = wred[0] + wred[1] + wred[2] + wred[3];
    const float inv = 1.f / s;
#pragma unroll
    for (int q = 0; q < 8; ++q)
        out[(size_t)bb * SDIM + q * 256 + tid] = e[q] * inv;
}

extern "C" void kernel_launch(void* const* d_in, const int* in_sizes, int n_in,
                              void* d_out, int out_size, void* d_ws, size_t ws_size,
                              hipStream_t stream) {
    const float* hidden = (const float*)d_in[0];   // (1, 32, 1024)
    const float* enc    = (const float*)d_in[1];   // (32, 2048, 1024)
    const float* W      = (const float*)d_in[2];   // (1024, 2048)
    const float* battn  = (const float*)d_in[3];   // (1024,)
    const float* v      = (const float*)d_in[4];   // (1024,)
    float* out = (float*)d_out;                    // (32, 2048)

    char* ws = (char*)d_ws;
    float* c             = (float*)ws;                           // 128 KB
    float* part          = (float*)(ws + (128 << 10));           // 512 KB
    unsigned short* Wbf2 = (unsigned short*)(ws + (640 << 10));  // 2 MB

    hipLaunchKernelGGL(prep,       dim3(1536), dim3(256), 0, stream, W, Wbf2, hidden, battn, c);
    hipLaunchKernelGGL(attn_fused, dim3(1024), dim3(512), 0, stream, enc, Wbf2, c, v, part);
    hipLaunchKernelGGL(softmax_k,  dim3(32),   dim3(256), 0, stream, part, out);
}

// Round 5
// 486.238 us; speedup vs baseline: 1.1495x; 1.1495x over previous
//
#include <hip/hip_runtime.h>
#include <hip/hip_bf16.h>
#include <cstdint>

// Problem: B=32, S=2048, H=1024
//   c[b,o]   = hidden[b,:].Wh[o,:] + bias[o]        (Wh = W_attn[:, :H])
//   e[b,s,o] = enc[b,s,:].We[o,:]                   (We = W_attn[:, H:])
//   logit[b,s] = sum_o tanh(e + c) * v[o];  out = softmax over s
//
// R7 = R5 (known-good 211us schedule, no spills) +
//  - XCD-paired block swizzle (proven in R6: FETCH 279->171 MB)
//  - pack2 via __float22bfloat162_rn -> v_cvt_pk_bf16_f32 (RNE, ~4x less
//    staging VALU than manual bit-twiddle)
//  - B-frag prefetch issued BEFORE af ds_reads each step (LDS-read burst
//    overlaps L2 latency)
// R6's depth-2 B prefetch is reverted: it spilled (WRITE_SIZE 39MB).

#define HDIM 1024
#define SDIM 2048
#define MTOT 65536

typedef __attribute__((ext_vector_type(8))) short short8;   // 8 bf16
typedef __attribute__((ext_vector_type(4))) float floatx4;  // MFMA acc

__device__ __forceinline__ unsigned int pack2(float a, float b) {
    __hip_bfloat162 h = __float22bfloat162_rn(float2{a, b});
    union { __hip_bfloat162 h; unsigned int u; } cv;
    cv.h = h;
    return cv.u;
}
__device__ __forceinline__ float fast_tanh(float x) {
    float e2 = __expf(2.f * x);
    return 1.f - 2.f * __builtin_amdgcn_rcpf(e2 + 1.f);
}

// ---- merged prep kernel ----
// blocks [0,512):   convert We (W_attn[:, H:2H]) into fragment-major bf16 Wbf2
// blocks [512,1536): c[b,o] = hidden[b,:].Wh[o,:] + bias[o], one block per o
__global__ __launch_bounds__(256) void prep(const float* __restrict__ W,
                                            unsigned short* __restrict__ Wbf2,
                                            const float* __restrict__ hid,
                                            const float* __restrict__ bias,
                                            float* __restrict__ c) {
    __shared__ float red[4][32];
    if (blockIdx.x < 512) {
        int T = blockIdx.x * 256 + threadIdx.x;   // [0, 131072): (n, k8)
        int n  = T >> 7;
        int k8 = T & 127;
        int k  = k8 * 8;
        const float4* src = (const float4*)(W + (size_t)n * 2048 + 1024 + k);
        float4 f0 = src[0], f1 = src[1];
        int jt = n >> 4, lc = n & 15, kc = k8 >> 2, g = k8 & 3;
        uint4 u;
        u.x = pack2(f0.x, f0.y); u.y = pack2(f0.z, f0.w);
        u.z = pack2(f1.x, f1.y); u.w = pack2(f1.z, f1.w);
        *(uint4*)(Wbf2 + (size_t)(jt * 32 + kc) * 512 + (g * 16 + lc) * 8) = u;
    } else {
        const int o = blockIdx.x - 512;
        const int wave = threadIdx.x >> 6, lane = threadIdx.x & 63;
        const int k = wave * 256 + lane * 4;
        const float4 wv = *(const float4*)(W + (size_t)o * 2048 + k);
        float acc[32];
#pragma unroll
        for (int b = 0; b < 32; ++b) {
            const float4 h = *(const float4*)(hid + b * HDIM + k);
            acc[b] = wv.x * h.x + wv.y * h.y + wv.z * h.z + wv.w * h.w;
        }
#pragma unroll
        for (int b = 0; b < 32; ++b) {
            float x = acc[b];
            for (int off = 32; off; off >>= 1) x += __shfl_xor(x, off);
            if (lane == 0) red[wave][b] = x;
        }
        __syncthreads();
        if (threadIdx.x < 32) {
            int b = threadIdx.x;
            c[b * HDIM + o] = red[0][b] + red[1][b] + red[2][b] + red[3][b] + bias[o];
        }
    }
}

// ---- fused GEMM + tanh + v-dot ----
#define PHN 8     // K phases
#define PHK 128   // K per phase

__global__ __launch_bounds__(512, 2) void attn_fused(const float* __restrict__ enc,
                                                     const unsigned short* __restrict__ Wbf2,
                                                     const float* __restrict__ c,
                                                     const float* __restrict__ v,
                                                     float* __restrict__ part) {
    // slab: 128 rows x 128 k bf16, row stride 128 ushorts (256B); 16B chunk c16
    // of row r stored at slot (c16 ^ (r&7)).
    __shared__ __align__(16) unsigned short slab[2][128 * 128];   // 2 x 32 KB

    const int tid  = threadIdx.x;
    const int lane = tid & 63;
    const int wave = tid >> 6;    // 0..7
    const int grp  = lane >> 4;   // 0..3
    const int lc   = lane & 15;

    // XCD-paired decode: phys j -> XCD j%8; (strip, nhalf=0/1) land on the
    // same XCD 8 dispatch-slots apart. Bijective for 1024 blocks.
    const int j     = blockIdx.x;
    const int strip = (j & 7) * 64 + (j >> 4);   // 0..511
    const int nhalf = (j >> 3) & 1;
    const int m0 = strip * 128;
    const int b  = m0 >> 11;      // batch (128-row strips never straddle b)
    const int cb = nhalf * 512 + wave * 64;      // wave's global col base

    // staging geometry: wave covers rows [wave*16, wave*16+16); q in [0,8):
    //   row = wave*16 + q*2 + (lane>>5),  kk = (lane&31)*4
    const int s_kk   = (lane & 31) * 4;
    const int s_rsub = lane >> 5;
    const int s_c16  = (lane & 31) >> 1;
    const int s_b8   = lane & 1;

    floatx4 acc[8][4];
#pragma unroll
    for (int i = 0; i < 8; ++i)
#pragma unroll
        for (int jj = 0; jj < 4; ++jj) acc[i][jj] = (floatx4){0.f, 0.f, 0.f, 0.f};

    const short8* Bfr = (const short8*)Wbf2;
    const int jt0 = nhalf * 32 + wave * 4;    // wave's first 16-col B tile

    float4 ld[8];
    // prologue: stage phase 0 into buf 0
#pragma unroll
    for (int q = 0; q < 8; ++q) {
        int row = wave * 16 + q * 2 + s_rsub;
        ld[q] = *(const float4*)(enc + (size_t)(m0 + row) * HDIM + s_kk);
    }
#pragma unroll
    for (int q = 0; q < 8; ++q) {
        int row  = wave * 16 + q * 2 + s_rsub;
        int slot = s_c16 ^ (row & 7);
        uint2 u = {pack2(ld[q].x, ld[q].y), pack2(ld[q].z, ld[q].w)};
        *(uint2*)(&slab[0][row * 128 + slot * 8 + s_b8 * 4]) = u;
    }

    // B lookahead ring: bf holds frags for current K-32 step
    short8 bf[4], bn[4];
#pragma unroll
    for (int jj = 0; jj < 4; ++jj)
        bf[jj] = Bfr[(size_t)((jt0 + jj) * 32 + 0) * 64 + lane];

#pragma unroll 1
    for (int p = 0; p < PHN; ++p) {
        __syncthreads();   // slab[p&1] fully written

        if (p < PHN - 1) {
#pragma unroll
            for (int q = 0; q < 8; ++q) {
                int row = wave * 16 + q * 2 + s_rsub;
                ld[q] = *(const float4*)(enc + (size_t)(m0 + row) * HDIM +
                                         (p + 1) * PHK + s_kk);
            }
        }

        const unsigned short* sl = slab[p & 1];
#pragma unroll
        for (int s = 0; s < 4; ++s) {                 // kc = s (K-32 sub-step)
            const int kc = s;
            // prefetch B for step s+1 FIRST (L2 latency overlaps af ds_reads;
            // crosses into next phase at s==3)
            {
                const int kc2 = (s + 1) & 3;
                const int pn  = (s < 3) ? p : ((p < PHN - 1) ? p + 1 : p);
#pragma unroll
                for (int jj = 0; jj < 4; ++jj)
                    bn[jj] = Bfr[(size_t)((jt0 + jj) * 32 + pn * 4 + kc2) * 64 + lane];
            }
            short8 af[8];
#pragma unroll
            for (int i = 0; i < 8; ++i) {
                int row  = i * 16 + lc;
                int slot = (kc * 4 + grp) ^ (lc & 7);
                af[i] = *(const short8*)(sl + row * 128 + slot * 8);
            }
#pragma unroll
            for (int i = 0; i < 8; ++i)
#pragma unroll
                for (int jj = 0; jj < 4; ++jj)
                    acc[i][jj] = __builtin_amdgcn_mfma_f32_16x16x32_bf16(
                        af[i], bf[jj], acc[i][jj], 0, 0, 0);
#pragma unroll
            for (int jj = 0; jj < 4; ++jj) bf[jj] = bn[jj];
        }

        if (p < PHN - 1) {
#pragma unroll
            for (int q = 0; q < 8; ++q) {
                int row  = wave * 16 + q * 2 + s_rsub;
                int slot = s_c16 ^ (row & 7);
                uint2 u = {pack2(ld[q].x, ld[q].y), pack2(ld[q].z, ld[q].w)};
                *(uint2*)(&slab[(p + 1) & 1][row * 128 + slot * 8 + s_b8 * 4]) = u;
            }
        }
    }

    // epilogue: rowsum over this wave's 64 cols, tanh(e + c) * v
    float rowsum[8][4];
#pragma unroll
    for (int i = 0; i < 8; ++i)
#pragma unroll
        for (int r = 0; r < 4; ++r) rowsum[i][r] = 0.f;

#pragma unroll
    for (int jj = 0; jj < 4; ++jj) {
        const int n  = cb + jj * 16 + lc;
        const float vn = v[n];
        const float cv = c[b * HDIM + n];
#pragma unroll
        for (int i = 0; i < 8; ++i)
#pragma unroll
            for (int r = 0; r < 4; ++r)
                rowsum[i][r] = fmaf(fast_tanh(acc[i][jj][r] + cv), vn,
                                    rowsum[i][r]);
    }

    // in-block reduction across the 8 waves (disjoint 64-col slices, same
    // 128 rows). red overlays slab (no LDS reads after final barrier).
    __syncthreads();
    float* red = (float*)slab;
#pragma unroll
    for (int i = 0; i < 8; ++i)
#pragma unroll
        for (int r = 0; r < 4; ++r) {
            float x = rowsum[i][r];
            x += __shfl_xor(x, 8);
            x += __shfl_xor(x, 4);
            x += __shfl_xor(x, 2);
            x += __shfl_xor(x, 1);
            if (lc == 0) red[wave * 128 + i * 16 + grp * 4 + r] = x;
        }
    __syncthreads();
    if (tid < 128) {
        float ssum = 0.f;
#pragma unroll
        for (int w = 0; w < 8; ++w) ssum += red[w * 128 + tid];
        part[(size_t)nhalf * MTOT + m0 + tid] = ssum;
    }
}

// ---- softmax over S=2048 per batch, summing 2 partial col-half slices ----
__global__ __launch_bounds__(256) void softmax_k(const float* __restrict__ part,
                                                 float* __restrict__ out) {
    __shared__ float wred[4];
    const int bb = blockIdx.x;
    const int tid = threadIdx.x;
    const int wave = tid >> 6, lane = tid & 63;

    float vals[8];
    float lmax = -INFINITY;
#pragma unroll
    for (int q = 0; q < 8; ++q) {
        const size_t idx = (size_t)bb * SDIM + q * 256 + tid;
        vals[q] = part[idx] + part[(size_t)MTOT + idx];
        lmax = fmaxf(lmax, vals[q]);
    }
    for (int off = 32; off; off >>= 1) lmax = fmaxf(lmax, __shfl_xor(lmax, off));
    if (lane == 0) wred[wave] = lmax;
    __syncthreads();
    lmax = fmaxf(fmaxf(wred[0], wred[1]), fmaxf(wred[2], wred[3]));
    __syncthreads();

    float e[8];
    float s = 0.f;
#pragma unroll
    for (int q = 0; q < 8; ++q) {
        e[q] = __expf(vals[q] - lmax);
        s += e[q];
    }
    for (int off = 32; off; off >>= 1) s += __shfl_xor(s, off);
    if (lane == 0) wred[wave] = s;
    __syncthreads();
    s = wred[0] + wred[1] + wred[2] + wred[3];
    const float inv = 1.f / s;
#pragma unroll
    for (int q = 0; q < 8; ++q)
        out[(size_t)bb * SDIM + q * 256 + tid] = e[q] * inv;
}

extern "C" void kernel_launch(void* const* d_in, const int* in_sizes, int n_in,
                              void* d_out, int out_size, void* d_ws, size_t ws_size,
                              hipStream_t stream) {
    const float* hidden = (const float*)d_in[0];   // (1, 32, 1024)
    const float* enc    = (const float*)d_in[1];   // (32, 2048, 1024)
    const float* W      = (const float*)d_in[2];   // (1024, 2048)
    const float* battn  = (const float*)d_in[3];   // (1024,)
    const float* v      = (const float*)d_in[4];   // (1024,)
    float* out = (float*)d_out;                    // (32, 2048)

    char* ws = (char*)d_ws;
    float* c             = (float*)ws;                           // 128 KB
    float* part          = (float*)(ws + (128 << 10));           // 512 KB
    unsigned short* Wbf2 = (unsigned short*)(ws + (640 << 10));  // 2 MB

    hipLaunchKernelGGL(prep,       dim3(1536), dim3(256), 0, stream, W, Wbf2, hidden, battn, c);
    hipLaunchKernelGGL(attn_fused, dim3(1024), dim3(512), 0, stream, enc, Wbf2, c, v, part);
    hipLaunchKernelGGL(softmax_k,  dim3(32),   dim3(256), 0, stream, part, out);
}